// Round 7
// baseline (234.474 us; speedup 1.0000x reference)
//
#include <hip/hip_runtime.h>

// HistogramLoss on MI355X — fused pairwise-cosine + soft-histogram + loss.
// Round 7: 2-phase double-buffered LDS GEMM using global_load_lds (zero-VGPR
// async staging the compiler can't sink — Round 6's register pipeline was
// defeated by load-sinking, VGPR=84). Split-bf16 product as one K=1536 GEMM:
// virtual-K regions [hi*hi | lo*hi | hi*lo] via per-step plane selection.

#define N_PTS   4096
#define DIM     512
#define TSIZE   151
#define HALF_T  75
#define BM      128
#define BK      64                  // u16 elems per row per tile (128B rows)
#define NSTEP   24                  // K' = 3*512 / BK
#define NTILES  32
#define NBLOCKS 528                 // 32*33/2 = 8*66 (XCD-bijective)
#define P_TOTAL 8386560u
#define STEPF   (2.0f / 150.0f)
#define STEPINV 75.0f
#define NCOPY   8
#define HSTRIDE 309                 // mod 32 = 21: copies bank-distinct

typedef short bfrag __attribute__((ext_vector_type(8)));   // 8 bf16
typedef float ffrag __attribute__((ext_vector_type(4)));   // 4 f32
typedef unsigned short u16;
typedef unsigned int   u32;

__device__ __forceinline__ ffrag mfma16(bfrag a, bfrag b, ffrag c) {
  return __builtin_amdgcn_mfma_f32_16x16x32_bf16(a, b, c, 0, 0, 0);
}

__device__ __forceinline__ void split4(float4 v, uint2* hi, uint2* lo) {
  u32 u0 = __float_as_uint(v.x), u1 = __float_as_uint(v.y);
  u32 u2 = __float_as_uint(v.z), u3 = __float_as_uint(v.w);
  float r0 = v.x - __uint_as_float(u0 & 0xFFFF0000u);   // exact residual
  float r1 = v.y - __uint_as_float(u1 & 0xFFFF0000u);
  float r2 = v.z - __uint_as_float(u2 & 0xFFFF0000u);
  float r3 = v.w - __uint_as_float(u3 & 0xFFFF0000u);
  hi->x = (u0 >> 16) | (u1 & 0xFFFF0000u);
  hi->y = (u2 >> 16) | (u3 & 0xFFFF0000u);
  lo->x = (__float_as_uint(r0) >> 16) | (__float_as_uint(r1) & 0xFFFF0000u);
  lo->y = (__float_as_uint(r2) >> 16) | (__float_as_uint(r3) & 0xFFFF0000u);
}

__device__ __forceinline__ void tile_decode(int orig, int* bi_, int* bj_) {
  int sbid = (orig & 7) * 66 + (orig >> 3);      // XCD-bijective (528 = 8*66)
  int rem = sbid, cnt = NTILES, bi = 0;
  while (rem >= cnt) { rem -= cnt; --cnt; ++bi; }
  *bi_ = bi; *bj_ = bi + rem;
}

// stage one 128x64 A-tile + B-tile for virtual-K step s into (Ad, Bd).
// Source is pre-swizzled so a linear global_load_lds write + XOR-swizzled
// ds_read compose to the identity (rule #21). swzk = ((l&7)^(l>>3))<<3.
__device__ __forceinline__ void stage_step(
    int s, u16* Ad, u16* Bd,
    const u16* __restrict__ Fhi, const u16* __restrict__ Flo,
    int rowA, int rowB, int w, int rseg, int swzk)
{
  const int region = s >> 3;                 // 0: hi*hi, 1: lo*hi, 2: hi*lo
  const int k0 = (s & 7) * BK;
  const u16* ap = (region == 1) ? Flo : Fhi;
  const u16* bp = (region == 2) ? Flo : Fhi;
  #pragma unroll
  for (int g = 0; g < 4; ++g) {
    int seg = w * 4 + g;                     // 1KB segment = 8 rows
    int row = seg * 8 + rseg;
    size_t ga = (size_t)(rowA + row) * DIM + k0 + swzk;
    size_t gb = (size_t)(rowB + row) * DIM + k0 + swzk;
    __builtin_amdgcn_global_load_lds(
        (const __attribute__((address_space(1))) unsigned int*)(ap + ga),
        (__attribute__((address_space(3))) unsigned int*)(Ad + seg * 512),
        16, 0, 0);
    __builtin_amdgcn_global_load_lds(
        (const __attribute__((address_space(1))) unsigned int*)(bp + gb),
        (__attribute__((address_space(3))) unsigned int*)(Bd + seg * 512),
        16, 0, 0);
  }
}

__device__ __forceinline__ void compute_step(
    const u16* As, const u16* Bs, ffrag (&acc)[4][4],
    int wy, int wx, int l4, int l16)
{
  const int swz = (l16 & 7) << 3;
  #pragma unroll
  for (int ks = 0; ks < 2; ++ks) {
    bfrag a[4], b[4];
    #pragma unroll
    for (int f = 0; f < 4; ++f) {
      int ra = wy * 64 + f * 16 + l16;
      int rb = wx * 64 + f * 16 + l16;
      int ko = (ks * 32 + l4 * 8) ^ swz;
      a[f] = *(const bfrag*)(As + ra * BK + ko);
      b[f] = *(const bfrag*)(Bs + rb * BK + ko);
    }
    #pragma unroll
    for (int fj = 0; fj < 4; ++fj)
      #pragma unroll
      for (int fi = 0; fi < 4; ++fi)
        acc[fi][fj] = mfma16(a[fi], b[fj], acc[fi][fj]);
  }
}

__device__ __forceinline__ void bin_epilogue(
    const ffrag (&acc)[4][4], float* h, const int* clsA, const int* clsB,
    int wy, int wx, int l4, int l16, bool diag, u32* myPos)
{
  #pragma unroll
  for (int fi = 0; fi < 4; ++fi) {
    #pragma unroll
    for (int fj = 0; fj < 4; ++fj) {
      #pragma unroll
      for (int r = 0; r < 4; ++r) {
        // C/D layout (m89/m91): row = 4*(lane>>4)+reg, col = lane&15
        int li = wy * 64 + fi * 16 + l4 * 4 + r;
        int lj = wx * 64 + fj * 16 + l16;
        if (diag && li >= lj) continue;
        float s  = acc[fi][fj][r];
        float jf = floorf(s * STEPINV);
        int   jb = (int)jf + HALF_T;
        float f  = jf * STEPF;
        float wa = (s - f) * STEPINV;
        float wb = (f + STEPF - s) * STEPINV;
        bool  pos = (clsA[li] == clsB[lj]);
        *myPos += pos ? 1u : 0u;
        int off = pos ? 0 : TSIZE;
        if (jb >= 0 && jb < TSIZE)         unsafeAtomicAdd(h + off + jb, wa);
        if (jb + 1 >= 0 && jb + 1 < TSIZE) unsafeAtomicAdd(h + off + jb + 1, wb);
      }
    }
  }
}

// ---- pass 1: split F -> row-major bf16 planes Fhi/Flo [4096][512] ----
__global__ __launch_bounds__(256) void presplit(
    const float* __restrict__ F, u16* __restrict__ Fhi, u16* __restrict__ Flo,
    float* __restrict__ g_hist, u32* __restrict__ g_pos)
{
  int u = blockIdx.x * 256 + threadIdx.x;   // u = row*64 + kb
  int row = u >> 6, kb = u & 63;
  const float* src = F + (size_t)row * DIM + kb * 8;
  float4 v0 = *(const float4*)(src);
  float4 v1 = *(const float4*)(src + 4);
  uint2 h0, l0, h1, l1;
  split4(v0, &h0, &l0);
  split4(v1, &h1, &l1);
  uint4 hv; hv.x = h0.x; hv.y = h0.y; hv.z = h1.x; hv.w = h1.y;
  uint4 lv; lv.x = l0.x; lv.y = l0.y; lv.z = l1.x; lv.w = l1.y;
  size_t dst = (size_t)row * DIM + kb * 8;  // coalesced reads AND writes
  *(uint4*)(Fhi + dst) = hv;
  *(uint4*)(Flo + dst) = lv;
  if (blockIdx.x == 0) {
    for (int i = threadIdx.x; i < 2 * TSIZE; i += 256) g_hist[i] = 0.0f;
    if (threadIdx.x == 0) *g_pos = 0u;
  }
}

// ---- pass 2: 2-phase double-buffered MFMA GEMM (K' = 1536) ----
__global__ __launch_bounds__(256, 2) void hist_mfma(
    const u16* __restrict__ Fhi, const u16* __restrict__ Flo,
    const int* __restrict__ cls,
    float* __restrict__ g_hist, u32* __restrict__ g_pos)
{
  __shared__ __align__(16) u16 As0[BM * BK];   // 16 KB each
  __shared__ __align__(16) u16 As1[BM * BK];
  __shared__ __align__(16) u16 Bs0[BM * BK];
  __shared__ __align__(16) u16 Bs1[BM * BK];
  __shared__ float hist[NCOPY * HSTRIDE];
  __shared__ int clsA[BM], clsB[BM];
  __shared__ u32 posCount;

  const int t = threadIdx.x;
  int bi, bj;
  tile_decode((int)blockIdx.x, &bi, &bj);
  const int rowA = bi * BM, rowB = bj * BM;

  for (int i = t; i < NCOPY * HSTRIDE; i += 256) hist[i] = 0.0f;
  if (t < BM) clsA[t] = cls[rowA + t];
  else        clsB[t - BM] = cls[rowB + (t - BM)];
  if (t == 0) posCount = 0u;

  const int lane = t & 63, w = t >> 6;
  const int wy = w >> 1, wx = w & 1;          // wave -> 64x64 quadrant
  const int l4 = lane >> 4, l16 = lane & 15;
  const int rseg = lane >> 3;                 // row within 8-row segment
  const int swzk = ((lane & 7) ^ (lane >> 3)) << 3;   // pre-swizzle, u16 units

  ffrag acc[4][4] = {};

  stage_step(0, As0, Bs0, Fhi, Flo, rowA, rowB, w, rseg, swzk);
  __syncthreads();                            // vmcnt(0) drain + hist init

  #pragma unroll 1
  for (int s2 = 0; s2 < NSTEP / 2; ++s2) {
    const int s = s2 * 2;
    if (s + 1 < NSTEP) stage_step(s + 1, As1, Bs1, Fhi, Flo, rowA, rowB, w, rseg, swzk);
    compute_step(As0, Bs0, acc, wy, wx, l4, l16);
    __syncthreads();
    if (s + 2 < NSTEP) stage_step(s + 2, As0, Bs0, Fhi, Flo, rowA, rowB, w, rseg, swzk);
    compute_step(As1, Bs1, acc, wy, wx, l4, l16);
    __syncthreads();
  }

  u32 myPos = 0;
  float* h = hist + (lane & 7) * HSTRIDE;     // adjacent lanes -> distinct copies
  bin_epilogue(acc, h, clsA, clsB, wy, wx, l4, l16, bi == bj, &myPos);
  atomicAdd(&posCount, myPos);
  __syncthreads();

  for (int i = t; i < 2 * TSIZE; i += 256) {
    float v = 0.0f;
    #pragma unroll
    for (int c = 0; c < NCOPY; ++c) v += hist[c * HSTRIDE + i];
    unsafeAtomicAdd(g_hist + i, v);
  }
  if (t == 0) atomicAdd(g_pos, posCount);
}

__global__ __launch_bounds__(256) void finalize(
    const float* __restrict__ g_hist,
    const u32* __restrict__ g_pos,
    float* __restrict__ out)
{
  __shared__ float hp[TSIZE];
  __shared__ float hn[TSIZE];
  __shared__ float red[4];
  const int t = threadIdx.x;
  const float Np = (float)(*g_pos);
  const float Nn = (float)(P_TOTAL - *g_pos);
  if (t < TSIZE) {
    hp[t] = g_hist[t] / Np;
    hn[t] = g_hist[TSIZE + t] / Nn;
  }
  __syncthreads();
  for (int off = 1; off < TSIZE; off <<= 1) {
    float v = 0.0f;
    if (t < TSIZE && t >= off) v = hp[t - off];
    __syncthreads();
    if (t < TSIZE) hp[t] += v;
    __syncthreads();
  }
  float term = (t < TSIZE) ? hn[t] * hp[t] : 0.0f;
  #pragma unroll
  for (int o = 32; o > 0; o >>= 1) term += __shfl_down(term, o);
  if ((t & 63) == 0) red[t >> 6] = term;
  __syncthreads();
  if (t == 0) *out = red[0] + red[1] + red[2] + red[3];
}

extern "C" void kernel_launch(void* const* d_in, const int* in_sizes, int n_in,
                              void* d_out, int out_size, void* d_ws, size_t ws_size,
                              hipStream_t stream) {
  const float* F   = (const float*)d_in[0];
  const int*   cls = (const int*)d_in[1];
  float* g_hist = (float*)d_ws;
  u32*   g_pos  = (u32*)((char*)d_ws + 2 * TSIZE * sizeof(float));
  float* out = (float*)d_out;

  const size_t offH = 65536;
  u16* Fhi = (u16*)((char*)d_ws + offH);
  u16* Flo = (u16*)((char*)d_ws + offH + (size_t)N_PTS * DIM * sizeof(u16));

  presplit<<<(N_PTS * 64) / 256, 256, 0, stream>>>(F, Fhi, Flo, g_hist, g_pos);
  hist_mfma<<<NBLOCKS, 256, 0, stream>>>(Fhi, Flo, cls, g_hist, g_pos);
  finalize<<<1, 256, 0, stream>>>(g_hist, g_pos, out);
}

// Round 8
// 219.906 us; speedup vs baseline: 1.0662x; 1.0662x over previous
//
#include <hip/hip_runtime.h>

// HistogramLoss on MI355X — fused pairwise-cosine + soft-histogram + loss.
// Round 8: XCD-clique schedule. All three prior GEMM structures hit the same
// ~160-175 µs wall with all pipes idle: operand reads were remote-L2/L3
// round-trips. This round pins each XCD to a <=4MB panel clique (band-pair)
// so every staged read is a LOCAL L2 hit, and runs 3 blocks/CU (43.6 KB LDS,
// single-buffer) for m114-style inter-block latency hiding. GEMM math,
// swizzle, and epilogue are identical to the absmax-0.0 Round-7 kernel.

#define N_PTS   4096
#define DIM     512
#define TSIZE   151
#define HALF_T  75
#define BM      128
#define BK      64                  // u16 elems per row per tile (128B rows)
#define NSTEP   24                  // K' = 3*512 / BK
#define P_TOTAL 8386560u
#define STEPF   (2.0f / 150.0f)
#define STEPINV 75.0f
#define NCOPY   8
#define HSTRIDE 309                 // mod 32 = 21: copies bank-distinct
#define GRID    576                 // 8 XCD lists x 72 slots (48 idle)

typedef short bfrag __attribute__((ext_vector_type(8)));   // 8 bf16
typedef float ffrag __attribute__((ext_vector_type(4)));   // 4 f32
typedef unsigned short u16;
typedef unsigned int   u32;

__device__ __forceinline__ ffrag mfma16(bfrag a, bfrag b, ffrag c) {
  return __builtin_amdgcn_mfma_f32_16x16x32_bf16(a, b, c, 0, 0, 0);
}

__device__ __forceinline__ void split4(float4 v, uint2* hi, uint2* lo) {
  u32 u0 = __float_as_uint(v.x), u1 = __float_as_uint(v.y);
  u32 u2 = __float_as_uint(v.z), u3 = __float_as_uint(v.w);
  float r0 = v.x - __uint_as_float(u0 & 0xFFFF0000u);   // exact residual
  float r1 = v.y - __uint_as_float(u1 & 0xFFFF0000u);
  float r2 = v.z - __uint_as_float(u2 & 0xFFFF0000u);
  float r3 = v.w - __uint_as_float(u3 & 0xFFFF0000u);
  hi->x = (u0 >> 16) | (u1 & 0xFFFF0000u);
  hi->y = (u2 >> 16) | (u3 & 0xFFFF0000u);
  lo->x = (__float_as_uint(r0) >> 16) | (__float_as_uint(r1) & 0xFFFF0000u);
  lo->y = (__float_as_uint(r2) >> 16) | (__float_as_uint(r3) & 0xFFFF0000u);
}

// XCD-clique pair decode: bid -> (bi,bj) such that each XCD (bid&7) only
// touches a <=4MB panel set. Bands of 8 tiles (2MB hi+lo each):
//   XCD 0-5: one inter-band pair (64 slots; 64-71 idle)
//   XCD 6:   intra-triangles of bands 0,1 (36+36 slots)
//   XCD 7:   intra-triangles of bands 2,3 (36+36 slots)
__device__ __forceinline__ bool tile_decode(int bid, int* bi_, int* bj_) {
  const int xcd = bid & 7, slot = bid >> 3;
  if (xcd < 6) {
    if (slot >= 64) return false;
    const int BA[6] = {0, 0, 0, 1, 1, 2};
    const int BB[6] = {1, 2, 3, 2, 3, 3};
    *bi_ = BA[xcd] * 8 + (slot >> 3);
    *bj_ = BB[xcd] * 8 + (slot & 7);
  } else {
    int p = slot;
    int band = (xcd - 6) * 2 + (p >= 36 ? 1 : 0);
    if (p >= 36) p -= 36;
    int rem = p, cnt = 8, ii = 0;
    while (rem >= cnt) { rem -= cnt; --cnt; ++ii; }
    *bi_ = band * 8 + ii;
    *bj_ = band * 8 + ii + rem;
  }
  return true;
}

// stage one 128x64 A-tile + B-tile for virtual-K step s (pre-swizzled source,
// linear global_load_lds dest — rule #21; identical to Round 7).
__device__ __forceinline__ void stage_step(
    int s, u16* Ad, u16* Bd,
    const u16* __restrict__ Fhi, const u16* __restrict__ Flo,
    int rowA, int rowB, int w, int rseg, int swzk)
{
  const int region = s >> 3;                 // 0: hi*hi, 1: lo*hi, 2: hi*lo
  const int k0 = (s & 7) * BK;
  const u16* ap = (region == 1) ? Flo : Fhi;
  const u16* bp = (region == 2) ? Flo : Fhi;
  #pragma unroll
  for (int g = 0; g < 4; ++g) {
    int seg = w * 4 + g;                     // 1KB segment = 8 rows
    int row = seg * 8 + rseg;
    size_t ga = (size_t)(rowA + row) * DIM + k0 + swzk;
    size_t gb = (size_t)(rowB + row) * DIM + k0 + swzk;
    __builtin_amdgcn_global_load_lds(
        (const __attribute__((address_space(1))) unsigned int*)(ap + ga),
        (__attribute__((address_space(3))) unsigned int*)(Ad + seg * 512),
        16, 0, 0);
    __builtin_amdgcn_global_load_lds(
        (const __attribute__((address_space(1))) unsigned int*)(bp + gb),
        (__attribute__((address_space(3))) unsigned int*)(Bd + seg * 512),
        16, 0, 0);
  }
}

__device__ __forceinline__ void compute_step(
    const u16* As, const u16* Bs, ffrag (&acc)[4][4],
    int wy, int wx, int l4, int l16)
{
  const int swz = (l16 & 7) << 3;
  #pragma unroll
  for (int ks = 0; ks < 2; ++ks) {
    bfrag a[4], b[4];
    #pragma unroll
    for (int f = 0; f < 4; ++f) {
      int ra = wy * 64 + f * 16 + l16;
      int rb = wx * 64 + f * 16 + l16;
      int ko = (ks * 32 + l4 * 8) ^ swz;
      a[f] = *(const bfrag*)(As + ra * BK + ko);
      b[f] = *(const bfrag*)(Bs + rb * BK + ko);
    }
    #pragma unroll
    for (int fj = 0; fj < 4; ++fj)
      #pragma unroll
      for (int fi = 0; fi < 4; ++fi)
        acc[fi][fj] = mfma16(a[fi], b[fj], acc[fi][fj]);
  }
}

__device__ __forceinline__ void bin_epilogue(
    const ffrag (&acc)[4][4], float* h, const int* clsA, const int* clsB,
    int wy, int wx, int l4, int l16, bool diag, u32* myPos)
{
  #pragma unroll
  for (int fi = 0; fi < 4; ++fi) {
    #pragma unroll
    for (int fj = 0; fj < 4; ++fj) {
      #pragma unroll
      for (int r = 0; r < 4; ++r) {
        // C/D layout (m89/m91): row = 4*(lane>>4)+reg, col = lane&15
        int li = wy * 64 + fi * 16 + l4 * 4 + r;
        int lj = wx * 64 + fj * 16 + l16;
        if (diag && li >= lj) continue;
        float s  = acc[fi][fj][r];
        float jf = floorf(s * STEPINV);
        int   jb = (int)jf + HALF_T;
        float f  = jf * STEPF;
        float wa = (s - f) * STEPINV;
        float wb = (f + STEPF - s) * STEPINV;
        bool  pos = (clsA[li] == clsB[lj]);
        *myPos += pos ? 1u : 0u;
        int off = pos ? 0 : TSIZE;
        if (jb >= 0 && jb < TSIZE)         unsafeAtomicAdd(h + off + jb, wa);
        if (jb + 1 >= 0 && jb + 1 < TSIZE) unsafeAtomicAdd(h + off + jb + 1, wb);
      }
    }
  }
}

// ---- pass 1: split F -> row-major bf16 planes Fhi/Flo [4096][512] ----
__global__ __launch_bounds__(256) void presplit(
    const float* __restrict__ F, u16* __restrict__ Fhi, u16* __restrict__ Flo,
    float* __restrict__ g_hist, u32* __restrict__ g_pos)
{
  int u = blockIdx.x * 256 + threadIdx.x;   // u = row*64 + kb
  int row = u >> 6, kb = u & 63;
  const float* src = F + (size_t)row * DIM + kb * 8;
  float4 v0 = *(const float4*)(src);
  float4 v1 = *(const float4*)(src + 4);
  uint2 h0, l0, h1, l1;
  split4(v0, &h0, &l0);
  split4(v1, &h1, &l1);
  uint4 hv; hv.x = h0.x; hv.y = h0.y; hv.z = h1.x; hv.w = h1.y;
  uint4 lv; lv.x = l0.x; lv.y = l0.y; lv.z = l1.x; lv.w = l1.y;
  size_t dst = (size_t)row * DIM + kb * 8;  // coalesced reads AND writes
  *(uint4*)(Fhi + dst) = hv;
  *(uint4*)(Flo + dst) = lv;
  if (blockIdx.x == 0) {
    for (int i = threadIdx.x; i < 2 * TSIZE; i += 256) g_hist[i] = 0.0f;
    if (threadIdx.x == 0) *g_pos = 0u;
  }
}

// ---- pass 2: MFMA GEMM, single-buffer, 3 blocks/CU, XCD-local reads ----
__global__ __launch_bounds__(256, 3) void hist_mfma(
    const u16* __restrict__ Fhi, const u16* __restrict__ Flo,
    const int* __restrict__ cls,
    float* __restrict__ g_hist, u32* __restrict__ g_pos)
{
  __shared__ __align__(16) u16 As[BM * BK];    // 16 KB
  __shared__ __align__(16) u16 Bs[BM * BK];    // 16 KB
  __shared__ float hist[NCOPY * HSTRIDE];      // 9.9 KB
  __shared__ int clsA[BM], clsB[BM];
  __shared__ u32 posCount;

  int bi, bj;
  if (!tile_decode((int)blockIdx.x, &bi, &bj)) return;   // idle slot
  const int t = threadIdx.x;
  const int rowA = bi * BM, rowB = bj * BM;

  for (int i = t; i < NCOPY * HSTRIDE; i += 256) hist[i] = 0.0f;
  if (t < BM) clsA[t] = cls[rowA + t];
  else        clsB[t - BM] = cls[rowB + (t - BM)];
  if (t == 0) posCount = 0u;

  const int lane = t & 63, w = t >> 6;
  const int wy = w >> 1, wx = w & 1;          // wave -> 64x64 quadrant
  const int l4 = lane >> 4, l16 = lane & 15;
  const int rseg = lane >> 3;                 // row within 8-row segment
  const int swzk = ((lane & 7) ^ (lane >> 3)) << 3;   // pre-swizzle, u16 units

  ffrag acc[4][4] = {};

  #pragma unroll 1
  for (int s = 0; s < NSTEP; ++s) {
    __syncthreads();                          // prev compute done (+init vis)
    stage_step(s, As, Bs, Fhi, Flo, rowA, rowB, w, rseg, swzk);
    __syncthreads();                          // vmcnt(0) drain
    compute_step(As, Bs, acc, wy, wx, l4, l16);
  }

  u32 myPos = 0;
  float* h = hist + (lane & 7) * HSTRIDE;     // adjacent lanes -> distinct copies
  bin_epilogue(acc, h, clsA, clsB, wy, wx, l4, l16, bi == bj, &myPos);
  atomicAdd(&posCount, myPos);
  __syncthreads();

  for (int i = t; i < 2 * TSIZE; i += 256) {
    float v = 0.0f;
    #pragma unroll
    for (int c = 0; c < NCOPY; ++c) v += hist[c * HSTRIDE + i];
    unsafeAtomicAdd(g_hist + i, v);
  }
  if (t == 0) atomicAdd(g_pos, posCount);
}

__global__ __launch_bounds__(256) void finalize(
    const float* __restrict__ g_hist,
    const u32* __restrict__ g_pos,
    float* __restrict__ out)
{
  __shared__ float hp[TSIZE];
  __shared__ float hn[TSIZE];
  __shared__ float red[4];
  const int t = threadIdx.x;
  const float Np = (float)(*g_pos);
  const float Nn = (float)(P_TOTAL - *g_pos);
  if (t < TSIZE) {
    hp[t] = g_hist[t] / Np;
    hn[t] = g_hist[TSIZE + t] / Nn;
  }
  __syncthreads();
  for (int off = 1; off < TSIZE; off <<= 1) {
    float v = 0.0f;
    if (t < TSIZE && t >= off) v = hp[t - off];
    __syncthreads();
    if (t < TSIZE) hp[t] += v;
    __syncthreads();
  }
  float term = (t < TSIZE) ? hn[t] * hp[t] : 0.0f;
  #pragma unroll
  for (int o = 32; o > 0; o >>= 1) term += __shfl_down(term, o);
  if ((t & 63) == 0) red[t >> 6] = term;
  __syncthreads();
  if (t == 0) *out = red[0] + red[1] + red[2] + red[3];
}

extern "C" void kernel_launch(void* const* d_in, const int* in_sizes, int n_in,
                              void* d_out, int out_size, void* d_ws, size_t ws_size,
                              hipStream_t stream) {
  const float* F   = (const float*)d_in[0];
  const int*   cls = (const int*)d_in[1];
  float* g_hist = (float*)d_ws;
  u32*   g_pos  = (u32*)((char*)d_ws + 2 * TSIZE * sizeof(float));
  float* out = (float*)d_out;

  const size_t offH = 65536;
  u16* Fhi = (u16*)((char*)d_ws + offH);
  u16* Flo = (u16*)((char*)d_ws + offH + (size_t)N_PTS * DIM * sizeof(u16));

  presplit<<<(N_PTS * 64) / 256, 256, 0, stream>>>(F, Fhi, Flo, g_hist, g_pos);
  hist_mfma<<<GRID, 256, 0, stream>>>(Fhi, Flo, cls, g_hist, g_pos);
  finalize<<<1, 256, 0, stream>>>(g_hist, g_pos, out);
}